// Round 14
// baseline (118.488 us; speedup 1.0000x reference)
//
#include <hip/hip_runtime.h>
#include <stdint.h>

#define N_PTS 256

typedef unsigned long long ull;
typedef float v2f __attribute__((ext_vector_type(2)));

// Single-inst DPP mov (old=0, bound_ctrl=1); row_ror rotates within 16-lane rows.
template<int CTRL>
__device__ __forceinline__ int dppmov(int x) {
    return __builtin_amdgcn_update_dpp(0, x, CTRL, 0xF, 0xF, true);
}

// All-lane min of f64 keys WITHIN each 16-lane row (4 independent rows share
// the same 4 DPP stages). Keys are tiny positive denormal doubles ->
// v_min_f64 == uint64 min (f64 denormals always on; no NaNs; hi <= 0xFF).
__device__ __forceinline__ double rowmin16(double x) {
    #define STAGE(C) { \
        ull u = __double_as_longlong(x); \
        int lo = dppmov<C>((int)(unsigned)u); \
        int hi = dppmov<C>((int)(unsigned)(u >> 32)); \
        double r = __longlong_as_double(((ull)(unsigned)hi << 32) | (unsigned)lo); \
        x = fmin(x, r); }
    STAGE(0x121)  // row_ror:1
    STAGE(0x122)  // row_ror:2
    STAGE(0x124)  // row_ror:4
    STAGE(0x128)  // row_ror:8
    #undef STAGE
    return x;
}

// Exact (dist, index) argmin over this row's 16 slots x 16 lanes.
// key = (dist_bits << 8) | k, k = slot*16 + rl; used slots get hi |= 0x80.
// Lexicographic min == reference's strict '<' first-min-wins, bit-exact.
__device__ __forceinline__ void reduce16(const float (&d)[16], unsigned used,
                                         unsigned rl16, unsigned& kk, unsigned& mu) {
    double kd[16];
    #pragma unroll
    for (int s = 0; s < 16; ++s) {
        unsigned du = __float_as_uint(d[s]);
        unsigned lo = (du << 8) | ((unsigned)(s << 4) | rl16);  // const folded
        unsigned hi = (du >> 24) | (((used >> s) & 1u) << 7);
        kd[s] = __longlong_as_double(((ull)hi << 32) | lo);
    }
    #pragma unroll
    for (int s = 0; s < 8; ++s) kd[s] = fmin(kd[s], kd[s + 8]);
    #pragma unroll
    for (int s = 0; s < 4; ++s) kd[s] = fmin(kd[s], kd[s + 4]);
    kd[0] = fmin(kd[0], kd[2]);
    kd[1] = fmin(kd[1], kd[3]);
    double km = rowmin16(fmin(kd[0], kd[1]));
    ull u = __double_as_longlong(km);
    unsigned lo = (unsigned)u, hi = (unsigned)(u >> 32);
    kk = lo & 0xFFu;
    mu = (lo >> 8) | (hi << 24);
}

__device__ __forceinline__ void finalize(unsigned kk, unsigned mu,
                                         unsigned& k, float& se) {
    const unsigned BIG_U = 0x47810200u;  // bits of 66049.0f = 257^2
    k  = (mu < BIG_U) ? kk : 0u;
    se = __uint_as_float(mu < BIG_U ? mu : BIG_U);
}

__device__ __forceinline__ void claim(unsigned sk, unsigned rl16, unsigned& used) {
    unsigned sbit = 1u << (sk >> 4);           // SALU
    used |= (rl16 == (sk & 15u)) ? sbit : 0u;  // v_cmp + cndmask + or
}

// One wave per batch; wave = 4 rows x 16 lanes; each row holds a replicated
// candidate set (16 slots/lane, k = slot*16 + rl) and processes target
// j = 4g + row speculatively; collisions redone exactly (R13-validated).
__global__ __launch_bounds__(256, 2) void greedy_match_kernel(
    const float* __restrict__ input,
    const float* __restrict__ targets,
    float* __restrict__ out,
    int B, float scale)
{
    __shared__ v2f   tl[4][N_PTS];
    __shared__ float wsum[4];

    const unsigned lane = threadIdx.x & 63;
    const int      wid  = threadIdx.x >> 6;
    const int      b    = blockIdx.x * 4 + wid;
    const bool     vB   = (b < B);
    const int      cb   = vB ? b : 0;

    const unsigned rl16 = lane & 15u;
    const unsigned rowv = lane >> 4;

    const v2f* pin = (const v2f*)(input   + (size_t)cb * (2 * N_PTS));
    const v2f* ptg = (const v2f*)(targets + (size_t)cb * (2 * N_PTS));

    #pragma unroll
    for (int c = 0; c < 4; ++c) {
        int idx = c * 64 + (int)lane;
        tl[wid][idx] = ptg[idx];
    }
    __syncthreads();
    const v2f* tlw = tl[wid];

    v2f p[16];
    #pragma unroll
    for (int s = 0; s < 16; ++s) p[s] = pin[(s << 4) + rl16];

    unsigned used = 0u;
    float acc = 0.0f;

    {
        #pragma clang fp contract(off)

        // distances for group 0 (dist does NOT depend on 'used' -> next
        // group's dists are computed during this group's tree+claims, giving
        // the scheduler fill for the f64-tree and claim-chain stalls)
        v2f tcur = tlw[rowv];
        float d[16];
        #pragma unroll
        for (int s = 0; s < 16; ++s) {
            v2f q = tcur - p[s];
            v2f qq = q * q;
            d[s] = qq.x + qq.y;
        }

        #pragma unroll 1
        for (int g = 0; g < 64; ++g) {
            // pipeline: group g+1 distances (pure f32 pk ops, independent)
            v2f tnext = tlw[(((g + 1) & 63) << 2) + rowv];
            float dn[16];
            #pragma unroll
            for (int s = 0; s < 16; ++s) {
                v2f q = tnext - p[s];
                v2f qq = q * q;
                dn[s] = qq.x + qq.y;
            }

            unsigned kk, mu, kf; float sef;
            reduce16(d, used, rl16, kk, mu);
            finalize(kk, mu, kf, sef);
            unsigned vk = kf; float vse = sef;

            unsigned k0 = (unsigned)__builtin_amdgcn_readlane((int)vk, 0);
            unsigned k1 = (unsigned)__builtin_amdgcn_readlane((int)vk, 16);
            unsigned k2 = (unsigned)__builtin_amdgcn_readlane((int)vk, 32);
            unsigned k3 = (unsigned)__builtin_amdgcn_readlane((int)vk, 48);

            // fast path: no pairwise collision (common) -> parallel claims
            bool c01 = (k1 == k0);
            bool c2  = (k2 == k0) | (k2 == k1);
            bool c3  = (k3 == k0) | (k3 == k1) | (k3 == k2);
            if (!(c01 | c2 | c3)) {
                unsigned m0 = (rl16 == (k0 & 15u)) ? (1u << (k0 >> 4)) : 0u;
                unsigned m1 = (rl16 == (k1 & 15u)) ? (1u << (k1 >> 4)) : 0u;
                unsigned m2 = (rl16 == (k2 & 15u)) ? (1u << (k2 >> 4)) : 0u;
                unsigned m3 = (rl16 == (k3 & 15u)) ? (1u << (k3 >> 4)) : 0u;
                used |= (m0 | m1) | (m2 | m3);
                acc += vse;
            } else {
                // exact serial path (R13): claim in row order, redo on collision
                claim(k0, rl16, used);
                if (k1 == k0) {
                    reduce16(d, used, rl16, kk, mu); finalize(kk, mu, kf, sef);
                    bool upd = (rowv >= 1u);
                    vk = upd ? kf : vk; vse = upd ? sef : vse;
                    k1 = (unsigned)__builtin_amdgcn_readlane((int)vk, 16);
                    k2 = (unsigned)__builtin_amdgcn_readlane((int)vk, 32);
                    k3 = (unsigned)__builtin_amdgcn_readlane((int)vk, 48);
                }
                claim(k1, rl16, used);
                if (k2 == k0 || k2 == k1) {
                    reduce16(d, used, rl16, kk, mu); finalize(kk, mu, kf, sef);
                    bool upd = (rowv >= 2u);
                    vk = upd ? kf : vk; vse = upd ? sef : vse;
                    k2 = (unsigned)__builtin_amdgcn_readlane((int)vk, 32);
                    k3 = (unsigned)__builtin_amdgcn_readlane((int)vk, 48);
                }
                claim(k2, rl16, used);
                if (k3 == k0 || k3 == k1 || k3 == k2) {
                    reduce16(d, used, rl16, kk, mu); finalize(kk, mu, kf, sef);
                    bool upd = (rowv >= 3u);
                    vk = upd ? kf : vk; vse = upd ? sef : vse;
                    k3 = (unsigned)__builtin_amdgcn_readlane((int)vk, 48);
                }
                claim(k3, rl16, used);
                acc += vse;
            }

            #pragma unroll
            for (int s = 0; s < 16; ++s) d[s] = dn[s];  // register rename
        }
    }

    // sum 4 row-subtotals: xor16 swizzle + xor32 bpermute
    int t1 = __builtin_amdgcn_ds_swizzle(__float_as_int(acc), 0x401F);
    float a2 = acc + __int_as_float(t1);
    int t2 = __builtin_amdgcn_ds_bpermute((int)((lane ^ 32u) << 2), __float_as_int(a2));
    float tot = a2 + __int_as_float(t2);

    if (lane == 0) wsum[wid] = vB ? tot : 0.0f;
    __syncthreads();
    if (threadIdx.x == 0) {
        float s = (wsum[0] + wsum[1] + wsum[2] + wsum[3]) * scale;
        atomicAdd(out, s);
    }
}

extern "C" void kernel_launch(void* const* d_in, const int* in_sizes, int n_in,
                              void* d_out, int out_size, void* d_ws, size_t ws_size,
                              hipStream_t stream) {
    const float* input   = (const float*)d_in[0];
    const float* targets = (const float*)d_in[1];
    float* out = (float*)d_out;

    const int B = in_sizes[0] / (2 * N_PTS);
    const float scale = 1.0f / ((float)B * (float)(2 * N_PTS));

    // d_out is poisoned 0xAA before every call — zero it (graph-capturable).
    hipMemsetAsync(d_out, 0, sizeof(float) * (size_t)out_size, stream);

    const int blocks = (B + 3) / 4;  // 4 waves (4 batches) per 256-thread block
    greedy_match_kernel<<<blocks, 256, 0, stream>>>(input, targets, out, B, scale);
}

// Round 16
// 109.510 us; speedup vs baseline: 1.0820x; 1.0820x over previous
//
#include <hip/hip_runtime.h>
#include <stdint.h>

#define N_PTS 256

typedef unsigned long long ull;
typedef float v2f __attribute__((ext_vector_type(2)));

// Single-inst DPP mov (old=0, bound_ctrl=1); row_ror rotates within 16-lane
// rows, no invalid lanes -> the 0 never appears.
template<int CTRL>
__device__ __forceinline__ int dppmov(int x) {
    return __builtin_amdgcn_update_dpp(0, x, CTRL, 0xF, 0xF, true);
}

// All-lane MAX of f64 keys WITHIN each 16-lane row (4 rows share the stages).
__device__ __forceinline__ double rowmax16(double x) {
    #define STAGE(C) { \
        ull u = __double_as_longlong(x); \
        int lo = dppmov<C>((int)(unsigned)u); \
        int hi = dppmov<C>((int)(unsigned)(u >> 32)); \
        double r = __longlong_as_double(((ull)(unsigned)hi << 32) | (unsigned)lo); \
        x = fmax(x, r); }
    STAGE(0x121)  // row_ror:1
    STAGE(0x122)  // row_ror:2
    STAGE(0x124)  // row_ror:4
    STAGE(0x128)  // row_ror:8
    #undef STAGE
    return x;
}

// Exact (dist, index) argmin via f64 MAX over keys:
//   hi = (used_s << 31) | (0x7F000000 - du)   [3 VALU: lshl, and_or, sub]
//   lo = 255 - k                              [loop-invariant constant!]
// 0x7F000000 - du: exact, strictly order-reversing, exponent < 0x7FF for all
// real du (N(0,1) data -> du << 0x7F000000) => positive double, no NaN.
// used slots: sign bit set -> negative double -> always lose fmax.
// hi-tie -> larger lo wins = smaller k = reference's first-min-wins. Bit-exact.
__device__ __forceinline__ void reduce16(const float (&d)[16], unsigned used,
                                         const unsigned (&lc)[16],
                                         unsigned& kk, unsigned& mu) {
    const unsigned SGN = 0x80000000u, KH = 0x7F000000u;
    double kd[16];
    #pragma unroll
    for (int s = 0; s < 16; ++s) {
        unsigned du = __float_as_uint(d[s]);
        unsigned t  = used << (31 - s);          // bit s -> sign position
        unsigned hi = (t & SGN) | (KH - du);     // v_and_or_b32 + v_sub
        kd[s] = __longlong_as_double(((ull)hi << 32) | lc[s]);
    }
    #pragma unroll
    for (int s = 0; s < 8; ++s) kd[s] = fmax(kd[s], kd[s + 8]);
    #pragma unroll
    for (int s = 0; s < 4; ++s) kd[s] = fmax(kd[s], kd[s + 4]);
    kd[0] = fmax(kd[0], kd[2]);
    kd[1] = fmax(kd[1], kd[3]);
    double km = rowmax16(fmax(kd[0], kd[1]));
    ull u = __double_as_longlong(km);
    kk = 255u - (unsigned)u;                     // lo = 255-k  ->  k
    mu = KH - (unsigned)(u >> 32);               // hi -> exact dist bits
}

__device__ __forceinline__ void finalize(unsigned kk, unsigned mu,
                                         unsigned& k, float& se) {
    const unsigned BIG_U = 0x47810200u;  // bits of 66049.0f = 257^2
    k  = (mu < BIG_U) ? kk : 0u;
    se = __uint_as_float(mu < BIG_U ? mu : BIG_U);
}

__device__ __forceinline__ void claim(unsigned sk, unsigned rl16, unsigned& used) {
    unsigned sbit = 1u << (sk >> 4);
    used |= (rl16 == (sk & 15u)) ? sbit : 0u;
}

// One wave per batch; wave = 4 rows x 16 lanes; each row = replicated
// candidate set (16 slots/lane, k = slot*16 + rl); 4 targets/group
// speculatively, collisions redone exactly (R13-validated).
__global__ __launch_bounds__(256, 2) void greedy_match_kernel(
    const float* __restrict__ input,
    const float* __restrict__ targets,
    float* __restrict__ out,
    int B, float scale)
{
    __shared__ v2f   tl[4][N_PTS];
    __shared__ float wsum[4];

    const unsigned lane = threadIdx.x & 63;
    const int      wid  = threadIdx.x >> 6;
    const int      b    = blockIdx.x * 4 + wid;
    const bool     vB   = (b < B);
    const int      cb   = vB ? b : 0;

    const unsigned rl16 = lane & 15u;
    const unsigned rowv = lane >> 4;

    const v2f* pin = (const v2f*)(input   + (size_t)cb * (2 * N_PTS));
    const v2f* ptg = (const v2f*)(targets + (size_t)cb * (2 * N_PTS));

    #pragma unroll
    for (int c = 0; c < 4; ++c) {
        int idx = c * 64 + (int)lane;
        tl[wid][idx] = ptg[idx];
    }
    __syncthreads();
    const v2f* tlw = tl[wid];

    v2f p[16];
    unsigned lc[16];
    #pragma unroll
    for (int s = 0; s < 16; ++s) {
        p[s]  = pin[(s << 4) + rl16];
        lc[s] = 255u - (unsigned)((s << 4) | rl16);
    }

    unsigned used = 0u;
    float acc = 0.0f;

    {
        #pragma clang fp contract(off)

        float dA[16], dB[16];
        {
            v2f t0 = tlw[rowv];
            #pragma unroll
            for (int s = 0; s < 16; ++s) {
                v2f q = t0 - p[s]; v2f qq = q * q; dA[s] = qq.x + qq.y;
            }
        }

        // one group-step: resolve from dcur; compute dnext (group g+1 dists,
        // independent of 'used') BETWEEN reduce and claims so the scheduler
        // fills the f64-tree + readlane latency; no register copies (R14's bug)
        #define STEP(dcur, dnext, g)                                          \
        {                                                                     \
            unsigned kk, mu, kf; float sef;                                   \
            reduce16(dcur, used, lc, kk, mu);                                 \
            finalize(kk, mu, kf, sef);                                        \
            unsigned vk = kf; float vse = sef;                                \
            v2f tn = tlw[((((g) + 1) & 63) << 2) + rowv];                     \
            _Pragma("unroll")                                                 \
            for (int s = 0; s < 16; ++s) {                                    \
                v2f q = tn - p[s]; v2f qq = q * q; (dnext)[s] = qq.x + qq.y;  \
            }                                                                 \
            unsigned k0 = (unsigned)__builtin_amdgcn_readlane((int)vk, 0);    \
            unsigned k1 = (unsigned)__builtin_amdgcn_readlane((int)vk, 16);   \
            unsigned k2 = (unsigned)__builtin_amdgcn_readlane((int)vk, 32);   \
            unsigned k3 = (unsigned)__builtin_amdgcn_readlane((int)vk, 48);   \
            claim(k0, rl16, used);                                            \
            if (k1 == k0) {                                                   \
                reduce16(dcur, used, lc, kk, mu); finalize(kk, mu, kf, sef);  \
                bool upd = (rowv >= 1u);                                      \
                vk = upd ? kf : vk; vse = upd ? sef : vse;                    \
                k1 = (unsigned)__builtin_amdgcn_readlane((int)vk, 16);        \
                k2 = (unsigned)__builtin_amdgcn_readlane((int)vk, 32);        \
                k3 = (unsigned)__builtin_amdgcn_readlane((int)vk, 48);        \
            }                                                                 \
            claim(k1, rl16, used);                                            \
            if (k2 == k0 || k2 == k1) {                                       \
                reduce16(dcur, used, lc, kk, mu); finalize(kk, mu, kf, sef);  \
                bool upd = (rowv >= 2u);                                      \
                vk = upd ? kf : vk; vse = upd ? sef : vse;                    \
                k2 = (unsigned)__builtin_amdgcn_readlane((int)vk, 32);        \
                k3 = (unsigned)__builtin_amdgcn_readlane((int)vk, 48);        \
            }                                                                 \
            claim(k2, rl16, used);                                            \
            if (k3 == k0 || k3 == k1 || k3 == k2) {                           \
                reduce16(dcur, used, lc, kk, mu); finalize(kk, mu, kf, sef);  \
                bool upd = (rowv >= 3u);                                      \
                vk = upd ? kf : vk; vse = upd ? sef : vse;                    \
                k3 = (unsigned)__builtin_amdgcn_readlane((int)vk, 48);        \
            }                                                                 \
            claim(k3, rl16, used);                                            \
            acc += vse;                                                      \
        }

        #pragma unroll 1
        for (int g = 0; g < 64; g += 2) {
            STEP(dA, dB, g)       // resolves group g,   preps dB
            STEP(dB, dA, g + 1)   // resolves group g+1, preps dA
        }
        #undef STEP
    }

    // sum 4 row-subtotals: xor16 swizzle + xor32 bpermute
    int t1 = __builtin_amdgcn_ds_swizzle(__float_as_int(acc), 0x401F);
    float a2 = acc + __int_as_float(t1);
    int t2 = __builtin_amdgcn_ds_bpermute((int)((lane ^ 32u) << 2), __float_as_int(a2));
    float tot = a2 + __int_as_float(t2);

    if (lane == 0) wsum[wid] = vB ? tot : 0.0f;
    __syncthreads();
    if (threadIdx.x == 0) {
        float s = (wsum[0] + wsum[1] + wsum[2] + wsum[3]) * scale;
        atomicAdd(out, s);
    }
}

extern "C" void kernel_launch(void* const* d_in, const int* in_sizes, int n_in,
                              void* d_out, int out_size, void* d_ws, size_t ws_size,
                              hipStream_t stream) {
    const float* input   = (const float*)d_in[0];
    const float* targets = (const float*)d_in[1];
    float* out = (float*)d_out;

    const int B = in_sizes[0] / (2 * N_PTS);
    const float scale = 1.0f / ((float)B * (float)(2 * N_PTS));

    // d_out is poisoned 0xAA before every call — zero it (graph-capturable).
    (void)hipMemsetAsync(d_out, 0, sizeof(float) * (size_t)out_size, stream);

    const int blocks = (B + 3) / 4;  // 4 waves (4 batches) per 256-thread block
    greedy_match_kernel<<<blocks, 256, 0, stream>>>(input, targets, out, B, scale);
}